// Round 12
// baseline (182.964 us; speedup 1.0000x reference)
//
#include <hip/hip_runtime.h>

#define BS 32
#define NA 512
#define ID 128
#define NH 8
#define HD 64
#define NHD 512   // NH*HD
#define NEG 0.2f
#define NC 32
#define CH 16
#define NSEG 16
#define SEG 32

// K1: h_prime = h @ W (fp32). EXACT R7 version (proven <43us). 16 rows x 512
// cols per block; wave-uniform A rows via s_load; dense 1KB W loads.
__global__ __launch_bounds__(256) void k1_gemm(
    const float* __restrict__ h, const float* __restrict__ W,
    const float* __restrict__ att, float* __restrict__ hp,
    float* __restrict__ s_out, float* __restrict__ t_out) {
  int blk = blockIdx.x;
  int b = blk >> 5;
  int n0 = (blk & 31) * 16;
  int t = threadIdx.x;
  int lane = t & 63, w = t >> 6;
  int r0 = __builtin_amdgcn_readfirstlane((w >> 1) * 8);   // 0 or 8
  int chalf = __builtin_amdgcn_readfirstlane(w & 1);
  int col = chalf * 256 + lane * 4;
  int head = col >> 6;
  int d0 = col & 63;
  const float* arow = h + ((size_t)b * NA + n0 + r0) * ID;  // uniform base
  const float* wptr = W + col;

  float4 a0c = {0,0,0,0}, a1c = {0,0,0,0}, a2c = {0,0,0,0}, a3c = {0,0,0,0};
  float4 a4c = {0,0,0,0}, a5c = {0,0,0,0}, a6c = {0,0,0,0}, a7c = {0,0,0,0};

#define K1_ROW(I, C, KK)                                                      \
  { float a_ = arow[(I) * ID + kc + (KK)];                                    \
    C.x += a_ * wv.x; C.y += a_ * wv.y; C.z += a_ * wv.z; C.w += a_ * wv.w; }
  #pragma unroll 1
  for (int kc = 0; kc < ID; kc += 8) {
    #pragma unroll
    for (int kk = 0; kk < 8; ++kk) {
      float4 wv = *(const float4*)(wptr + (size_t)(kc + kk) * NHD);
      K1_ROW(0, a0c, kk) K1_ROW(1, a1c, kk) K1_ROW(2, a2c, kk)
      K1_ROW(3, a3c, kk) K1_ROW(4, a4c, kk) K1_ROW(5, a5c, kk)
      K1_ROW(6, a6c, kk) K1_ROW(7, a7c, kk)
    }
  }
#undef K1_ROW
  {
    size_t off = ((((size_t)b * NH + head) * NA) + (n0 + r0)) * HD + d0;
    *(float4*)(hp + off) = a0c; off += HD;
    *(float4*)(hp + off) = a1c; off += HD;
    *(float4*)(hp + off) = a2c; off += HD;
    *(float4*)(hp + off) = a3c; off += HD;
    *(float4*)(hp + off) = a4c; off += HD;
    *(float4*)(hp + off) = a5c; off += HD;
    *(float4*)(hp + off) = a6c; off += HD;
    *(float4*)(hp + off) = a7c;
  }
  {
    float4 as4 = *(const float4*)(att + head * 128 + d0);
    float4 ad4 = *(const float4*)(att + head * 128 + 64 + d0);
#define DOT4(C, A) ((C).x*(A).x + (C).y*(A).y + (C).z*(A).z + (C).w*(A).w)
    float sp0 = DOT4(a0c, as4), tp0 = DOT4(a0c, ad4);
    float sp1 = DOT4(a1c, as4), tp1 = DOT4(a1c, ad4);
    float sp2 = DOT4(a2c, as4), tp2 = DOT4(a2c, ad4);
    float sp3 = DOT4(a3c, as4), tp3 = DOT4(a3c, ad4);
    float sp4 = DOT4(a4c, as4), tp4 = DOT4(a4c, ad4);
    float sp5 = DOT4(a5c, as4), tp5 = DOT4(a5c, ad4);
    float sp6 = DOT4(a6c, as4), tp6 = DOT4(a6c, ad4);
    float sp7 = DOT4(a7c, as4), tp7 = DOT4(a7c, ad4);
#undef DOT4
    #pragma unroll
    for (int m = 1; m < 16; m <<= 1) {
      sp0 += __shfl_xor(sp0, m, 64); tp0 += __shfl_xor(tp0, m, 64);
      sp1 += __shfl_xor(sp1, m, 64); tp1 += __shfl_xor(tp1, m, 64);
      sp2 += __shfl_xor(sp2, m, 64); tp2 += __shfl_xor(tp2, m, 64);
      sp3 += __shfl_xor(sp3, m, 64); tp3 += __shfl_xor(tp3, m, 64);
      sp4 += __shfl_xor(sp4, m, 64); tp4 += __shfl_xor(tp4, m, 64);
      sp5 += __shfl_xor(sp5, m, 64); tp5 += __shfl_xor(tp5, m, 64);
      sp6 += __shfl_xor(sp6, m, 64); tp6 += __shfl_xor(tp6, m, 64);
      sp7 += __shfl_xor(sp7, m, 64); tp7 += __shfl_xor(tp7, m, 64);
    }
    int g16 = lane & 15;
    int rsel = g16 & 7;
    float sv_ = rsel == 0 ? sp0 : rsel == 1 ? sp1 : rsel == 2 ? sp2 :
                rsel == 3 ? sp3 : rsel == 4 ? sp4 : rsel == 5 ? sp5 :
                rsel == 6 ? sp6 : sp7;
    float tv_ = rsel == 0 ? tp0 : rsel == 1 ? tp1 : rsel == 2 ? tp2 :
                rsel == 3 ? tp3 : rsel == 4 ? tp4 : rsel == 5 ? tp5 :
                rsel == 6 ? tp6 : tp7;
    size_t off = (((size_t)b * NH + head) * NA) + n0 + r0 + rsel;
    if (g16 < 8) s_out[off] = sv_;
    else         t_out[off] = tv_;
  }
}

// K2a: sort-only kernel (NO hp gathers). Double hybrid bitonic sort (t asc,
// s desc — R8-proven), wp/wn to global, exact scalar den tables, per-s-rank
// rinfo {A,B,1/den, js|row<<16}, per-segment start indices (js monotone).
__global__ __launch_bounds__(512) void k2a_sort(
    const float* __restrict__ s_g, const float* __restrict__ t_g,
    int* __restrict__ tpm_g, float* __restrict__ wp_g, float* __restrict__ wn_g,
    float4* __restrict__ rinfo_g, int* __restrict__ segStart_g) {
  __shared__ float tv[NA]; __shared__ int tpm[NA];
  __shared__ float sv[NA]; __shared__ int spm[NA];
  __shared__ float wp[NA]; __shared__ float wn[NA];
  __shared__ int aJ[NA];
  __shared__ float zps[NA + 1]; __shared__ float znp[NA + 1];
  __shared__ float szP[NC]; __shared__ float szN[NC];
  __shared__ float sufZ[NC + 1]; __shared__ float preZ[NC + 1];

  int bh = blockIdx.x;
  int t = threadIdx.x;

  // double hybrid bitonic sort (regs + shfl <64, LDS >=64) — R8-proven
  float tvr = t_g[(size_t)bh * NA + t]; int tir = t;
  float svr = s_g[(size_t)bh * NA + t]; int sir = t;
  for (int size = 2; size <= NA; size <<= 1) {
    bool dirAsc = ((t & size) == 0);
    for (int stride = size >> 1; stride > 0; stride >>= 1) {
      float ptv, psv; int pti, psi;
      if (stride >= 64) {
        tv[t] = tvr; tpm[t] = tir; sv[t] = svr; spm[t] = sir;
        __syncthreads();
        ptv = tv[t ^ stride]; pti = tpm[t ^ stride];
        psv = sv[t ^ stride]; psi = spm[t ^ stride];
        __syncthreads();
      } else {
        ptv = __shfl_xor(tvr, stride, 64); pti = __shfl_xor(tir, stride, 64);
        psv = __shfl_xor(svr, stride, 64); psi = __shfl_xor(sir, stride, 64);
      }
      bool mn = (((t & stride) == 0) == dirAsc);
      bool swt = mn ? (ptv < tvr) : (ptv > tvr);   // t ascending
      if (swt) { tvr = ptv; tir = pti; }
      bool sws = mn ? (psv > svr) : (psv < svr);   // s descending
      if (sws) { svr = psv; sir = psi; }
    }
  }
  tv[t] = tvr; tpm[t] = tir; sv[t] = svr; spm[t] = sir;
  __syncthreads();

  float cmax = fmaxf(tv[NA - 1], 0.f);
  float amax = fmaxf(sv[0], 0.f);              // s sorted descending
  float wpv = __expf(tv[t] - cmax);
  float wnv = __expf(NEG * tv[t] - cmax);
  wp[t] = wpv; wn[t] = wnv;
  tpm_g[(size_t)bh * NA + t] = tpm[t];
  wp_g[(size_t)bh * NA + t] = wpv;
  wn_g[(size_t)bh * NA + t] = wnv;
  __syncthreads();

  // scalar chunk sums for exact den tables
  if (t < 32) {
    float a = 0.f;
    for (int j = t * CH; j < t * CH + CH; ++j) a += wp[j];
    szP[t] = a;
  } else if (t < 64) {
    int c = t - 32; float a = 0.f;
    for (int j = c * CH; j < c * CH + CH; ++j) a += wn[j];
    szN[c] = a;
  }
  __syncthreads();
  if (t == 0) {
    float run = 0.f; sufZ[NC] = 0.f;
    for (int cc = NC - 1; cc >= 0; --cc) { run += szP[cc]; sufZ[cc] = run; }
  } else if (t == 1) {
    float run = 0.f;
    for (int cc = 0; cc <= NC; ++cc) { preZ[cc] = run; if (cc < NC) run += szN[cc]; }
  }
  __syncthreads();
  {
    int ch = t >> 4;
    float a = 0.f;
    for (int k = t; k < ch * CH + CH; ++k) a += wp[k];
    zps[t] = a + sufZ[ch + 1];
    float b2 = 0.f;
    for (int k = ch * CH; k < t; ++k) b2 += wn[k];
    znp[t] = preZ[ch] + b2;
    if (t == 0) { zps[NA] = 0.f; znp[NA] = preZ[NC]; }
  }
  __syncthreads();

  // per-s-rank rinfo (t = s-rank p): A,B, exact 1/den, packed js|row<<16
  {
    float sval = sv[t];
    int row = spm[t];
    float A = __expf(sval - amax);
    float B = __expf(NEG * sval - amax);
    float key = -sval;
    int lo = 0, hi = NA;
    while (lo < hi) { int mid = (lo + hi) >> 1; if (tv[mid] < key) lo = mid + 1; else hi = mid; }
    float den = A * zps[lo] + B * znp[lo];
    float4 ri;
    ri.x = A; ri.y = B; ri.z = 1.f / den;
    ri.w = __int_as_float(lo | (row << 16));
    rinfo_g[(size_t)bh * NA + t] = ri;
    aJ[t] = lo;
  }
  __syncthreads();

  // segment starts: segStart[g] = first s-rank p with js >= g*SEG (g=0..16)
  if (t <= NSEG) {
    int target = t * SEG;
    int lo = 0, hi = NA;
    while (lo < hi) { int mid = (lo + hi) >> 1; if (aJ[mid] < target) lo = mid + 1; else hi = mid; }
    segStart_g[bh * (NSEG + 1) + t] = lo;
  }
}

// K2b: per-segment local weighted V sums. 1024 blocks x 256 (4096 waves,
// 16 waves/CU) — 32 gathers per wave with deep wave-level latency hiding.
__global__ __launch_bounds__(256) void k2b_local(
    const float* __restrict__ hp, const int* __restrict__ tpm_g,
    const float* __restrict__ wp_g, const float* __restrict__ wn_g,
    float* __restrict__ localP_g, float* __restrict__ localN_g) {
  int blk = blockIdx.x;
  int bh = blk >> 2;
  int t = threadIdx.x;
  int lane = t & 63, w = t >> 6;
  int seg = (blk & 3) * 4 + w;
  int jb = seg * SEG;
  const float* vb = hp + (size_t)bh * NA * HD;
  const int* tpb = tpm_g + (size_t)bh * NA;
  const float* wpb = wp_g + (size_t)bh * NA;
  const float* wnb = wn_g + (size_t)bh * NA;
  float aP0 = 0.f, aP1 = 0.f, aP2 = 0.f, aP3 = 0.f;
  float aN0 = 0.f, aN1 = 0.f, aN2 = 0.f, aN3 = 0.f;
  #pragma unroll
  for (int i = 0; i < SEG; i += 4) {
    int j = jb + i;
    int4 tp4 = *(const int4*)(tpb + j);
    float4 wp4 = *(const float4*)(wpb + j);
    float4 wn4 = *(const float4*)(wnb + j);
    float v0 = vb[(size_t)tp4.x * HD + lane];
    float v1 = vb[(size_t)tp4.y * HD + lane];
    float v2 = vb[(size_t)tp4.z * HD + lane];
    float v3 = vb[(size_t)tp4.w * HD + lane];
    aP0 += wp4.x * v0; aN0 += wn4.x * v0;
    aP1 += wp4.y * v1; aN1 += wn4.y * v1;
    aP2 += wp4.z * v2; aN2 += wn4.z * v2;
    aP3 += wp4.w * v3; aN3 += wn4.w * v3;
  }
  localP_g[((size_t)bh * NSEG + seg) * 64 + lane] = (aP0 + aP1) + (aP2 + aP3);
  localN_g[((size_t)bh * NSEG + seg) * 64 + lane] = (aN0 + aN1) + (aN2 + aN3);
}

// K2c: per-segment stream + inline emission (R8 math, validated; now with
// 4096 independent waves). No tables: reads locals for seed, re-gathers own
// 32 rows, emits each output row the moment runP/runN reach its js.
__global__ __launch_bounds__(256) void k2c_emit(
    const float* __restrict__ hp, const int* __restrict__ tpm_g,
    const float* __restrict__ wp_g, const float* __restrict__ wn_g,
    const float* __restrict__ localP_g, const float* __restrict__ localN_g,
    const float4* __restrict__ rinfo_g, const int* __restrict__ segStart_g,
    float* __restrict__ out) {
  int blk = blockIdx.x;
  int bh = blk >> 2;
  int t = threadIdx.x;
  int lane = t & 63, w = t >> 6;
  int seg = (blk & 3) * 4 + w;
  int jb = seg * SEG;
  const float* vb = hp + (size_t)bh * NA * HD;
  const int* tpb = tpm_g + (size_t)bh * NA;
  const float* wpb = wp_g + (size_t)bh * NA;
  const float* wnb = wn_g + (size_t)bh * NA;
  const float4* rib = rinfo_g + (size_t)bh * NA;
  float* ob = out + (size_t)bh * NA * HD;

  // seed + total from local sums
  const float* lp = localP_g + (size_t)bh * NSEG * 64 + lane;
  const float* ln = localN_g + (size_t)bh * NSEG * 64 + lane;
  float seedP = 0.f, seedN = 0.f, totP = 0.f;
  #pragma unroll
  for (int u = 0; u < NSEG; ++u) {
    float xp = lp[u * 64];
    totP += xp;
    if (u < seg) { seedP += xp; seedN += ln[u * 64]; }
  }

  int p  = segStart_g[bh * (NSEG + 1) + seg];
  int p1 = segStart_g[bh * (NSEG + 1) + seg + 1];
  float runP = seedP, runN = seedN;
  for (int jj = 0; jj < SEG; ++jj) {
    int j = jb + jj;
    while (p < p1) {
      float4 ri = rib[p];
      int bits = __float_as_int(ri.w);
      if ((bits & 0xFFFF) != j) break;
      int row = bits >> 16;
      float x = (ri.x * (totP - runP) + ri.y * runN) * ri.z;
      ob[(size_t)row * HD + lane] = x > 0.f ? x : __expf(x) - 1.f;
      ++p;
    }
    int vr = tpb[j];
    float v = vb[(size_t)vr * HD + lane];
    runP += wpb[j] * v;
    runN += wnb[j] * v;
  }
  if (seg == NSEG - 1) {
    while (p < NA) {   // js == 512 rows (all scores negative-branch)
      float4 ri = rib[p];
      int bits = __float_as_int(ri.w);
      int row = bits >> 16;
      float x = (ri.x * (totP - runP) + ri.y * runN) * ri.z;
      ob[(size_t)row * HD + lane] = x > 0.f ? x : __expf(x) - 1.f;
      ++p;
    }
  }
}

extern "C" void kernel_launch(void* const* d_in, const int* in_sizes, int n_in,
                              void* d_out, int out_size, void* d_ws, size_t ws_size,
                              hipStream_t stream) {
  const float* h  = (const float*)d_in[0];
  const float* W  = (const float*)d_in[1];
  const float* att = (const float*)d_in[2];
  float* out = (float*)d_out;
  // ws floats: hp 8.39M | s 131k | t 131k | tpm 131k | wp 131k | wn 131k |
  // rinfo 524k | segStart 8k | localP 262k | localN 262k  (~40 MB)
  float* hp    = (float*)d_ws;
  float* s_arr = hp + (size_t)BS * NH * NA * HD;
  float* t_arr = s_arr + (size_t)BS * NH * NA;
  int*   tpm_g = (int*)(t_arr + (size_t)BS * NH * NA);
  float* wp_g  = (float*)(tpm_g + (size_t)BS * NH * NA);
  float* wn_g  = wp_g + (size_t)BS * NH * NA;
  float* rinfo = wn_g + (size_t)BS * NH * NA;
  int*   segS  = (int*)(rinfo + (size_t)BS * NH * NA * 4);
  float* locP  = (float*)(segS + (size_t)BS * NH * 32);
  float* locN  = locP + (size_t)BS * NH * NSEG * 64;

  k1_gemm <<<dim3(1024), dim3(256), 0, stream>>>(h, W, att, hp, s_arr, t_arr);
  k2a_sort<<<dim3(256),  dim3(512), 0, stream>>>(s_arr, t_arr, tpm_g, wp_g,
                                                 wn_g, (float4*)rinfo, segS);
  k2b_local<<<dim3(1024), dim3(256), 0, stream>>>(hp, tpm_g, wp_g, wn_g,
                                                  locP, locN);
  k2c_emit <<<dim3(1024), dim3(256), 0, stream>>>(hp, tpm_g, wp_g, wn_g,
                                                  locP, locN, (float4*)rinfo,
                                                  segS, out);
}